// Round 6
// baseline (271.722 us; speedup 1.0000x reference)
//
#include <hip/hip_runtime.h>

typedef __attribute__((ext_vector_type(8))) _Float16 f16x8;
typedef __attribute__((ext_vector_type(4))) float f32x4;
typedef __attribute__((ext_vector_type(16))) float f32x16;
typedef __attribute__((ext_vector_type(4))) unsigned u32x4;
typedef __attribute__((ext_vector_type(2))) unsigned u32x2;

#define EPSV 1e-5f
#define BB 8
#define CC 256
#define NP 4096
#define FF 128
#define SPLIT 4
#define CHUNK 1024
#define NIT 32

#define GLD16(gp, lp) __builtin_amdgcn_global_load_lds( \
    (const __attribute__((address_space(1))) unsigned int*)(gp), \
    (__attribute__((address_space(3))) unsigned int*)(lp), 16, 0, 0)

static __device__ __forceinline__ unsigned short f2h(float f) {
    union { _Float16 h; unsigned short u; } v;
    v.h = (_Float16)f;
    return v.u;
}
static __device__ __forceinline__ float h2f(unsigned short u) {
    union { unsigned short u; _Float16 h; } v;
    v.u = u;
    return (float)v.h;
}
// after: a = [a_lo, b_lo], b = [a_hi, b_hi]  (builtin: both results returned,
// no tied-operand register-coalescing hazard of the inline-asm form)
static __device__ __forceinline__ void plswap(unsigned& a, unsigned& b) {
    u32x2 r = __builtin_amdgcn_permlane32_swap(a, b, false, false);
    a = r[0]; b = r[1];
}
static __device__ __forceinline__ unsigned fbits(float f) { return __builtin_bit_cast(unsigned, f); }
static __device__ __forceinline__ float bitsf(unsigned u) { return __builtin_bit_cast(float, u); }

// ---------------------------------------------------------------- prep
struct PrepArgs {
    const float* w[3]; const float* bias[3]; const float* g[3]; const float* be[3];
    const float* m[3]; const float* v[3];
    const float* pre_w; const float* pre_b;
    const float* post_g; const float* post_be; const float* post_m; const float* post_v;
    unsigned short* W_all; float* b_all; unsigned short* W2; float* b2; float* sres;
};

__global__ __launch_bounds__(256) void prep_kernel(PrepArgs a) {
    int idx = blockIdx.x * 256 + threadIdx.x;
    if (idx < 3 * 128 * 256) {
        int row = idx >> 8, c = idx & 255;
        int which = row >> 7, f = row & 127;
        float s = a.g[which][f] * rsqrtf(a.v[which][f] + EPSV);
        a.W_all[idx] = f2h(a.w[which][f * 256 + c] * s);
        if (c == 0)
            a.b_all[row] = s * a.bias[which][f] + a.be[which][f] - a.m[which][f] * s;
    } else {
        int i = idx - 3 * 128 * 256;
        if (i < 256 * 128) {
            int c = i >> 7, f = i & 127;
            float s = a.post_g[c] * rsqrtf(a.post_v[c] + EPSV);
            a.W2[i] = f2h(a.pre_w[i] * s);
            if (f == 0) {
                a.b2[c] = s * a.pre_b[c] + a.post_be[c] - a.post_m[c] * s;
                a.sres[c] = s;
            }
        }
    }
}

// ---------------------------------------------------------------- transpose x -> xT f16
__global__ __launch_bounds__(256) void transpose_x_kernel(const float* __restrict__ x,
                                                          unsigned short* __restrict__ xT) {
    __shared__ float tile[64][65];
    int blk = blockIdx.x;           // 8 * 4 * 64
    int b  = blk >> 8;
    int c0 = ((blk >> 6) & 3) << 6;
    int n0 = (blk & 63) << 6;
    int t = threadIdx.x;
    const float* src = x + ((size_t)b * CC + c0) * NP + n0;
    #pragma unroll
    for (int i = 0; i < 16; ++i) {
        int cl = i * 4 + (t >> 6);
        tile[cl][t & 63] = src[(size_t)cl * NP + (t & 63)];
    }
    __syncthreads();
    unsigned short* dst = xT + ((size_t)b * NP + n0) * CC + c0;
    #pragma unroll
    for (int i = 0; i < 8; ++i) {
        int nl = i * 8 + (t >> 5);
        int cl = (t & 31) * 2;
        unsigned lo = f2h(tile[cl][nl]);
        unsigned hi = f2h(tile[cl + 1][nl]);
        *reinterpret_cast<unsigned*>(dst + (size_t)nl * CC + cl) = (hi << 16) | lo;
    }
}

// ---------------------------------------------------------------- qkv gemm
// Outputs in MFMA-frag-tiled layouts (per 32-row tile, per batch):
//   qT/kT: [tile][kf 0..7][h*32+r][j]  elem = X[tile*32+r][kf*16+h*8+j]
//   vT:    [mtile][fb*2+kb][h*32+rcol][j] elem = V[f=fb*32+rcol][m=mtile*32+kb*16+h*8+j]
__global__ __launch_bounds__(256) void qkv_kernel(const unsigned short* __restrict__ xT,
                                                  const unsigned short* __restrict__ W_all,
                                                  const float* __restrict__ b_all,
                                                  unsigned short* __restrict__ qT,
                                                  unsigned short* __restrict__ kT,
                                                  unsigned short* __restrict__ vT) {
    __shared__ unsigned short Alds[128 * 72];
    __shared__ unsigned short Blds[128 * 72];
    int blk = blockIdx.x;           // 768 = 8 batches * 3 ftiles * 32 ntiles
    int b  = blk & 7;               // XCD-affine batch
    int r  = blk >> 3;              // 0..95
    int ft = r >> 5;                // 0..2
    int n0 = (r & 31) << 7;
    int fbase = ft << 7;
    int t = threadIdx.x, w = t >> 6, l = t & 63;
    int wr = (w >> 1) << 6, wc = (w & 1) << 6;
    const unsigned short* A  = xT + ((size_t)b * NP + n0) * CC;
    const unsigned short* Bw = W_all + (size_t)fbase * CC;

    f32x4 acc[4][4];
    #pragma unroll
    for (int i = 0; i < 4; ++i)
        #pragma unroll
        for (int j = 0; j < 4; ++j)
            acc[i][j] = f32x4{0.f, 0.f, 0.f, 0.f};

    for (int c0 = 0; c0 < 256; c0 += 64) {
        #pragma unroll
        for (int i = 0; i < 4; ++i) {
            int row = i * 32 + (t >> 3);
            int ch = (t & 7) * 8;
            *reinterpret_cast<int4*>(&Alds[row * 72 + ch]) =
                *reinterpret_cast<const int4*>(A + (size_t)row * CC + c0 + ch);
            *reinterpret_cast<int4*>(&Blds[row * 72 + ch]) =
                *reinterpret_cast<const int4*>(Bw + (size_t)row * CC + c0 + ch);
        }
        __syncthreads();
        #pragma unroll
        for (int kk = 0; kk < 2; ++kk) {
            f16x8 af[4], bfr[4];
            #pragma unroll
            for (int mi = 0; mi < 4; ++mi)
                af[mi] = *reinterpret_cast<const f16x8*>(
                    &Alds[(wr + mi * 16 + (l & 15)) * 72 + kk * 32 + (l >> 4) * 8]);
            #pragma unroll
            for (int ni = 0; ni < 4; ++ni)
                bfr[ni] = *reinterpret_cast<const f16x8*>(
                    &Blds[(wc + ni * 16 + (l & 15)) * 72 + kk * 32 + (l >> 4) * 8]);
            #pragma unroll
            for (int mi = 0; mi < 4; ++mi)
                #pragma unroll
                for (int ni = 0; ni < 4; ++ni)
                    acc[mi][ni] = __builtin_amdgcn_mfma_f32_16x16x32_f16(af[mi], bfr[ni], acc[mi][ni], 0, 0, 0);
        }
        __syncthreads();
    }

    #pragma unroll
    for (int mi = 0; mi < 4; ++mi) {
        #pragma unroll
        for (int ni = 0; ni < 4; ++ni) {
            int fl = wc + ni * 16 + (l & 15);
            float bias = b_all[fbase + fl];
            int nb = n0 + wr + mi * 16 + ((l >> 4) << 2);
            float v0 = acc[mi][ni][0] + bias; v0 = v0 > 0.f ? v0 : 0.f;
            float v1 = acc[mi][ni][1] + bias; v1 = v1 > 0.f ? v1 : 0.f;
            float v2 = acc[mi][ni][2] + bias; v2 = v2 > 0.f ? v2 : 0.f;
            float v3 = acc[mi][ni][3] + bias; v3 = v3 > 0.f ? v3 : 0.f;
            if (ft == 2) {
                // V tiled: n is the m-index, fl the f-index
                int mtile = nb >> 5, kb = (nb >> 4) & 1, hh = (nb >> 3) & 1, j = nb & 7;
                int fb = fl >> 5, rcol = fl & 31;
                unsigned short* dst = vT + (size_t)b * NP * FF +
                    (size_t)mtile * 4096 + (size_t)(fb * 2 + kb) * 512 + (hh * 32 + rcol) * 8 + j;
                uint2 uu;
                uu.x = (unsigned)f2h(v0) | ((unsigned)f2h(v1) << 16);
                uu.y = (unsigned)f2h(v2) | ((unsigned)f2h(v3) << 16);
                *reinterpret_cast<uint2*>(dst) = uu;
            } else {
                unsigned short* dst = (ft == 0 ? qT : kT) + (size_t)b * NP * FF;
                int kf = fl >> 4, hh = (fl >> 3) & 1, j = fl & 7;
                unsigned short h0 = f2h(v0), h1 = f2h(v1), h2 = f2h(v2), h3 = f2h(v3);
                dst[(size_t)((nb + 0) >> 5) * 4096 + kf * 512 + (hh * 32 + ((nb + 0) & 31)) * 8 + j] = h0;
                dst[(size_t)((nb + 1) >> 5) * 4096 + kf * 512 + (hh * 32 + ((nb + 1) & 31)) * 8 + j] = h1;
                dst[(size_t)((nb + 2) >> 5) * 4096 + kf * 512 + (hh * 32 + ((nb + 2) & 31)) * 8 + j] = h2;
                dst[(size_t)((nb + 3) >> 5) * 4096 + kf * 512 + (hh * 32 + ((nb + 3) & 31)) * 8 + j] = h3;
            }
        }
    }
}

// ---------------------------------------------------------------- flash attention, split-KV x4
// KVBLK=32. K,Q frag-tiled from global -> registers (VMEM pipe, coalesced 1024B/wave);
// V frag-tiled via global_load_lds double-buffer (DS pipe, conflict-free linear reads);
// softmax fully in-register; cross-half exchange via v_permlane32_swap_b32 (VALU).
__global__ __launch_bounds__(256, 3) void attn_kernel(const unsigned short* __restrict__ qT,
                                                      const unsigned short* __restrict__ kT,
                                                      const unsigned short* __restrict__ vT,
                                                      unsigned short* __restrict__ Uh,
                                                      float2* __restrict__ ml) {
    __shared__ unsigned short Vl[2][4096];   // 8 KB per buffer
    int blk = blockIdx.x;            // 1024 = 8 b * (32 qt * 4 s)
    int b = blk & 7;                 // XCD-affine batch
    int rest = blk >> 3;
    int s = rest & 3;
    int qt = rest >> 2;
    int t = threadIdx.x, w = t >> 6, l = t & 63;
    int r = l & 31, h = l >> 5;
    int n0w = qt * 128 + w * 32;
    const unsigned short* Qb = qT + (size_t)b * NP * FF + (size_t)(qt * 4 + w) * 4096;
    const unsigned short* Kb = kT + (size_t)b * NP * FF + (size_t)(s * 32) * 4096;
    const unsigned short* Vb = vT + (size_t)b * NP * FF + (size_t)(s * 32) * 4096;

    f16x8 qf[8], kg[8];
    #pragma unroll
    for (int kf = 0; kf < 8; ++kf) {
        qf[kf] = *reinterpret_cast<const f16x8*>(Qb + kf * 512 + l * 8);
        kg[kf] = *reinterpret_cast<const f16x8*>(Kb + kf * 512 + l * 8);
    }
    // stage V tile 0 into buf 0
    GLD16(Vb + w * 512 + l * 8, &Vl[0][w * 512]);
    GLD16(Vb + 2048 + w * 512 + l * 8, &Vl[0][2048 + w * 512]);

    f32x16 U[4];
    #pragma unroll
    for (int fb = 0; fb < 4; ++fb)
        #pragma unroll
        for (int i = 0; i < 16; ++i) U[fb][i] = 0.f;
    float mrun = -1e30f, lrun = 0.f;

    int cur = 0;
    for (int it = 0; it < NIT; ++it) {
        asm volatile("s_waitcnt vmcnt(0)" ::: "memory");
        __builtin_amdgcn_s_barrier();
        asm volatile("" ::: "memory");
        if (it + 1 < NIT) {
            const unsigned short* vn = Vb + (size_t)(it + 1) * 4096;
            GLD16(vn + w * 512 + l * 8, &Vl[cur ^ 1][w * 512]);
            GLD16(vn + 2048 + w * 512 + l * 8, &Vl[cur ^ 1][2048 + w * 512]);
        }

        // S^T = K Q^T : 32m x 32n; lane owns col n = r, 16 m-values
        f32x16 St;
        #pragma unroll
        for (int i = 0; i < 16; ++i) St[i] = 0.f;
        __builtin_amdgcn_s_setprio(1);
        #pragma unroll
        for (int kf = 0; kf < 8; ++kf)
            St = __builtin_amdgcn_mfma_f32_32x32x16_f16(kg[kf], qf[kf], St, 0, 0, 0);
        __builtin_amdgcn_s_setprio(0);

        // refill K regs for next tile (VMEM, coalesced; lands before next iter's QK)
        if (it + 1 < NIT) {
            const unsigned short* kn = Kb + (size_t)(it + 1) * 4096;
            #pragma unroll
            for (int kf = 0; kf < 8; ++kf)
                kg[kf] = *reinterpret_cast<const f16x8*>(kn + kf * 512 + l * 8);
        }

        // online softmax (in-register, permlane cross-half)
        float pm0 = fmaxf(fmaxf(St[0], St[1]), fmaxf(St[2], St[3]));
        float pm1 = fmaxf(fmaxf(St[4], St[5]), fmaxf(St[6], St[7]));
        float pm2 = fmaxf(fmaxf(St[8], St[9]), fmaxf(St[10], St[11]));
        float pm3 = fmaxf(fmaxf(St[12], St[13]), fmaxf(St[14], St[15]));
        float pmax = fmaxf(fmaxf(pm0, pm1), fmaxf(pm2, pm3));
        { unsigned pa = fbits(pmax), pb = pa; plswap(pa, pb); pmax = fmaxf(bitsf(pa), bitsf(pb)); }
        if (__any(pmax > mrun + 8.0f)) {       // defer-max, THR=8
            float mnew = fmaxf(mrun, pmax);
            float sc = __expf(mrun - mnew);
            mrun = mnew; lrun *= sc;
            #pragma unroll
            for (int rr = 0; rr < 16; ++rr) {
                float scb = __shfl(sc, (rr & 3) + 8 * (rr >> 2) + 4 * h);
                U[0][rr] *= scb; U[1][rr] *= scb; U[2][rr] *= scb; U[3][rr] *= scb;
            }
        }
        float lsum = 0.f;
        unsigned pk[8];
        #pragma unroll
        for (int i = 0; i < 8; ++i) {
            float e0 = __expf(St[2 * i] - mrun);
            float e1 = __expf(St[2 * i + 1] - mrun);
            lsum += e0 + e1;
            pk[i] = __builtin_bit_cast(unsigned, __builtin_amdgcn_cvt_pkrtz(e0, e1));
        }
        { unsigned la = fbits(lsum), lb = la; plswap(la, lb); lsum = bitsf(la) + bitsf(lb); }
        lrun += lsum;

        // U += P V : A-frag rebuilt with 4 permlane swaps; V from LDS (conflict-free)
        const unsigned short* Vc = &Vl[cur][0];
        __builtin_amdgcn_s_setprio(1);
        #pragma unroll
        for (int kb = 0; kb < 2; ++kb) {
            unsigned a0 = pk[kb * 4 + 0], b0 = pk[kb * 4 + 2];
            unsigned a1 = pk[kb * 4 + 1], b1 = pk[kb * 4 + 3];
            plswap(a0, b0);
            plswap(a1, b1);
            u32x4 du; du[0] = a0; du[1] = a1; du[2] = b0; du[3] = b1;
            f16x8 af = __builtin_bit_cast(f16x8, du);
            #pragma unroll
            for (int fb = 0; fb < 4; ++fb) {
                f16x8 vf = *reinterpret_cast<const f16x8*>(Vc + (fb * 2 + kb) * 512 + l * 8);
                U[fb] = __builtin_amdgcn_mfma_f32_32x32x16_f16(af, vf, U[fb], 0, 0, 0);
            }
        }
        __builtin_amdgcn_s_setprio(0);
        cur ^= 1;
    }

    // partials: Uh[s][b][n][f] = U/l (f16), ml[s][b][n] = (m, l)
    float linv = 1.0f / lrun;
    unsigned short* up = Uh + (size_t)(s * 8 + b) * NP * FF;
    #pragma unroll
    for (int rr = 0; rr < 16; ++rr) {
        int nn = (rr & 3) + 8 * (rr >> 2) + 4 * h;
        float scb = __shfl(linv, nn);
        int n = n0w + nn;
        #pragma unroll
        for (int fb = 0; fb < 4; ++fb)
            up[(size_t)n * FF + fb * 32 + r] = f2h(U[fb][rr] * scb);
    }
    if (l < 32)
        ml[(size_t)(s * 8 + b) * NP + n0w + l] = make_float2(mrun, lrun);
}

// ---------------------------------------------------------------- combine split-KV partials
__global__ __launch_bounds__(256) void combine_kernel(const unsigned short* __restrict__ Uh,
                                                      const float2* __restrict__ ml,
                                                      unsigned short* __restrict__ uT) {
    int row = blockIdx.x * 2 + (threadIdx.x >> 7);   // b*4096 + n
    int f = threadIdx.x & 127;
    float m[SPLIT], lv[SPLIT];
    #pragma unroll
    for (int s = 0; s < SPLIT; ++s) {
        float2 v = ml[(size_t)s * (BB * NP) + row];
        m[s] = v.x; lv[s] = v.y;
    }
    float M = fmaxf(fmaxf(m[0], m[1]), fmaxf(m[2], m[3]));
    float wsum = 0.f, acc = 0.f;
    #pragma unroll
    for (int s = 0; s < SPLIT; ++s) {
        float wgt = __expf(m[s] - M) * lv[s];
        wsum += wgt;
        acc += wgt * h2f(Uh[((size_t)s * (BB * NP) + row) * FF + f]);
    }
    uT[(size_t)row * FF + f] = f2h(acc / wsum);
}

// ---------------------------------------------------------------- final gemm + residual + bn + relu
__global__ __launch_bounds__(256) void final_kernel(const unsigned short* __restrict__ uT,
                                                    const unsigned short* __restrict__ W2,
                                                    const float* __restrict__ b2,
                                                    const float* __restrict__ sres,
                                                    const float* __restrict__ x,
                                                    float* __restrict__ out) {
    __shared__ unsigned short Alds[128 * 72];
    __shared__ unsigned short Blds[128 * 72];
    int blk = blockIdx.x;           // 512 = 8 * 2 * 32
    int b  = blk & 7;
    int r  = blk >> 3;
    int ct = r & 1;
    int nt = r >> 1;
    int c0 = ct << 7, n0 = nt << 7;
    int t = threadIdx.x, w = t >> 6, l = t & 63;
    int wr = (w >> 1) << 6, wc = (w & 1) << 6;

    f32x4 acc[4][4];
    #pragma unroll
    for (int i = 0; i < 4; ++i)
        #pragma unroll
        for (int j = 0; j < 4; ++j)
            acc[i][j] = f32x4{0.f, 0.f, 0.f, 0.f};

    for (int k0 = 0; k0 < 128; k0 += 64) {
        #pragma unroll
        for (int i = 0; i < 4; ++i) {
            int row = i * 32 + (t >> 3);
            int ch = (t & 7) * 8;
            *reinterpret_cast<int4*>(&Alds[row * 72 + ch]) =
                *reinterpret_cast<const int4*>(W2 + (size_t)(c0 + row) * FF + k0 + ch);
            *reinterpret_cast<int4*>(&Blds[row * 72 + ch]) =
                *reinterpret_cast<const int4*>(uT + ((size_t)b * NP + n0 + row) * FF + k0 + ch);
        }
        __syncthreads();
        #pragma unroll
        for (int kk = 0; kk < 2; ++kk) {
            f16x8 af[4], bfr[4];
            #pragma unroll
            for (int mi = 0; mi < 4; ++mi)
                af[mi] = *reinterpret_cast<const f16x8*>(
                    &Alds[(wr + mi * 16 + (l & 15)) * 72 + kk * 32 + (l >> 4) * 8]);
            #pragma unroll
            for (int ni = 0; ni < 4; ++ni)
                bfr[ni] = *reinterpret_cast<const f16x8*>(
                    &Blds[(wc + ni * 16 + (l & 15)) * 72 + kk * 32 + (l >> 4) * 8]);
            #pragma unroll
            for (int mi = 0; mi < 4; ++mi)
                #pragma unroll
                for (int ni = 0; ni < 4; ++ni)
                    acc[mi][ni] = __builtin_amdgcn_mfma_f32_16x16x32_f16(af[mi], bfr[ni], acc[mi][ni], 0, 0, 0);
        }
        __syncthreads();
    }

    const float* xb = x + (size_t)b * CC * NP;
    float* ob = out + (size_t)b * CC * NP;
    #pragma unroll
    for (int mi = 0; mi < 4; ++mi)
        #pragma unroll
        for (int ni = 0; ni < 4; ++ni) {
            int n = n0 + wc + ni * 16 + (l & 15);
            int cb = c0 + wr + mi * 16 + ((l >> 4) << 2);
            #pragma unroll
            for (int rg = 0; rg < 4; ++rg) {
                int c = cb + rg;
                float v = acc[mi][ni][rg] + b2[c] + sres[c] * xb[(size_t)c * NP + n];
                ob[(size_t)c * NP + n] = v > 0.f ? v : 0.f;
            }
        }
}

// ---------------------------------------------------------------- launch
extern "C" void kernel_launch(void* const* d_in, const int* in_sizes, int n_in,
                              void* d_out, int out_size, void* d_ws, size_t ws_size,
                              hipStream_t stream) {
    const float* x = (const float*)d_in[0];
    char* ws = (char*)d_ws;
    // ws layout (bytes)
    unsigned short* W_all = (unsigned short*)(ws);                    // 384*256*2   = 196608
    float*          b_all = (float*)(ws + 196608);                    // 384*4
    unsigned short* W2    = (unsigned short*)(ws + 198144);           // 256*128*2
    float*          b2    = (float*)(ws + 263680);
    float*          sres  = (float*)(ws + 264704);
    unsigned short* xT    = (unsigned short*)(ws + 265728);           // 8*4096*256*2 = 16777216
    unsigned short* qT    = (unsigned short*)(ws + 17042944);         // 8*4096*128*2 = 8388608
    unsigned short* kT    = (unsigned short*)(ws + 25431552);
    unsigned short* vT    = (unsigned short*)(ws + 33820160);
    unsigned short* uT    = (unsigned short*)(ws + 42208768);
    unsigned short* Uh    = (unsigned short*)(ws + 50597376);         // 4*8*4096*128*2 = 33554432
    float2*         ml    = (float2*)(ws + 84151808);                 // 4*8*4096*8 = 1048576
    // end 85200384

    PrepArgs pa;
    pa.w[0]  = (const float*)d_in[1];  pa.bias[0] = (const float*)d_in[2];
    pa.g[0]  = (const float*)d_in[3];  pa.be[0]   = (const float*)d_in[4];
    pa.m[0]  = (const float*)d_in[5];  pa.v[0]    = (const float*)d_in[6];
    pa.w[1]  = (const float*)d_in[7];  pa.bias[1] = (const float*)d_in[8];
    pa.g[1]  = (const float*)d_in[9];  pa.be[1]   = (const float*)d_in[10];
    pa.m[1]  = (const float*)d_in[11]; pa.v[1]    = (const float*)d_in[12];
    pa.w[2]  = (const float*)d_in[13]; pa.bias[2] = (const float*)d_in[14];
    pa.g[2]  = (const float*)d_in[15]; pa.be[2]   = (const float*)d_in[16];
    pa.m[2]  = (const float*)d_in[17]; pa.v[2]    = (const float*)d_in[18];
    pa.pre_w = (const float*)d_in[19]; pa.pre_b   = (const float*)d_in[20];
    pa.post_g = (const float*)d_in[21]; pa.post_be = (const float*)d_in[22];
    pa.post_m = (const float*)d_in[23]; pa.post_v  = (const float*)d_in[24];
    pa.W_all = W_all; pa.b_all = b_all; pa.W2 = W2; pa.b2 = b2; pa.sres = sres;

    prep_kernel<<<dim3(512), dim3(256), 0, stream>>>(pa);
    transpose_x_kernel<<<dim3(2048), dim3(256), 0, stream>>>(x, xT);
    qkv_kernel<<<dim3(768), dim3(256), 0, stream>>>(xT, W_all, b_all, qT, kT, vT);
    attn_kernel<<<dim3(1024), dim3(256), 0, stream>>>(qT, kT, vT, Uh, ml);
    combine_kernel<<<dim3(16384), dim3(256), 0, stream>>>(Uh, ml, uT);
    final_kernel<<<dim3(512), dim3(256), 0, stream>>>(uT, W2, b2, sres, x, (float*)d_out);
}